// Round 1
// baseline (304.854 us; speedup 1.0000x reference)
//
#include <hip/hip_runtime.h>
#include <hip/hip_bf16.h>

// ---------- types ----------
typedef __attribute__((ext_vector_type(8))) short short8;   // 8 bf16 (4 VGPR)
typedef __attribute__((ext_vector_type(4))) short short4v;  // 4 bf16
typedef __attribute__((ext_vector_type(4))) float f32x4;

#define B_SZ   512
#define N_BOX  64
#define D_IN   2048
#define D_OUT  1024
#define M_ROWS (B_SZ * N_BOX)   // 32768

__device__ __forceinline__ short f2bf(float x) {
    union { __hip_bfloat16 h; short s; } u;
    u.h = __float2bfloat16(x);
    return u.s;
}
__device__ __forceinline__ float bf2f(short s) {
    union { short s; __hip_bfloat16 h; } u;
    u.s = s;
    return __bfloat162float(u.h);
}

// ---------- 1. cast img_feats f32 -> bf16 ----------
__global__ void cast_a_kernel(const float* __restrict__ in,
                              short* __restrict__ out, int n8) {
    int i = blockIdx.x * blockDim.x + threadIdx.x;
    int stride = gridDim.x * blockDim.x;
    for (int j = i; j < n8; j += stride) {
        long e = (long)j * 8;
        float4 v0 = *(const float4*)(in + e);
        float4 v1 = *(const float4*)(in + e + 4);
        short8 o;
        o[0] = f2bf(v0.x); o[1] = f2bf(v0.y); o[2] = f2bf(v0.z); o[3] = f2bf(v0.w);
        o[4] = f2bf(v1.x); o[5] = f2bf(v1.y); o[6] = f2bf(v1.z); o[7] = f2bf(v1.w);
        *(short8*)(out + e) = o;
    }
}

// ---------- 2. W [2048][1024] f32 -> Bt [1024][2048] bf16 ----------
__global__ void transpose_w_kernel(const float* __restrict__ W,
                                   short* __restrict__ Bt) {
    __shared__ float tile[32][33];
    int c0 = blockIdx.x * 32;       // n dim (1024/32 = 32)
    int r0 = blockIdx.y * 32;       // k dim (2048/32 = 64)
    int tc = threadIdx.x & 31;
    int tr = threadIdx.x >> 5;      // 0..7
#pragma unroll
    for (int i = 0; i < 32; i += 8)
        tile[tr + i][tc] = W[(long)(r0 + tr + i) * D_OUT + c0 + tc];
    __syncthreads();
#pragma unroll
    for (int i = 0; i < 32; i += 8)
        Bt[(long)(c0 + tr + i) * D_IN + r0 + tc] = f2bf(tile[tc][tr + i]);
}

// ---------- 3. GEMM (bf16 MFMA) + bias + ReLU, h -> bf16 ----------
#define BM 128
#define BN 128
#define BK 32

__global__ void gemm_bias_relu_kernel(const short* __restrict__ A,   // [32768][2048] bf16
                                      const short* __restrict__ Bt,  // [1024][2048] bf16
                                      const float* __restrict__ bias,
                                      short* __restrict__ H) {       // [32768][1024] bf16
    const int K = D_IN;
    __shared__ short As[BM * BK];   // 8 KB, linear [128][32]
    __shared__ short Bs[BN * BK];   // 8 KB

    // XCD-bijective swizzle: nwg = 2048, 8 XCDs, chunk = 256.
    int bid = blockIdx.x;
    int lid = (bid & 7) * 256 + (bid >> 3);
    int bm = lid & 255;   // 0..255  (M fastest within XCD chunk)
    int bn = lid >> 8;    // 0..7    (each XCD owns one B panel)

    int tid  = threadIdx.x;
    int wave = tid >> 6;
    int lane = tid & 63;
    int wm = wave >> 1, wn = wave & 1;      // 2x2 wave grid, 64x64 each
    int lrow = lane & 15;
    int lko  = (lane >> 4) * 8;             // K element offset in fragment

    f32x4 acc[4][4];
#pragma unroll
    for (int i = 0; i < 4; i++)
#pragma unroll
        for (int j = 0; j < 4; j++) acc[i][j] = (f32x4)0.0f;

    const long a_base = (long)bm * BM * K;
    const long b_base = (long)bn * BN * K;

    int srow = tid >> 2;            // 0..63
    int scol = (tid & 3) * 8;       // 0,8,16,24

    for (int k0 = 0; k0 < K; k0 += BK) {
        // stage A (2 issues) + B (2 issues), 16B/lane, LDS linear in tid
        __builtin_amdgcn_global_load_lds(
            (const __attribute__((address_space(1))) void*)(A + a_base + (long)srow * K + k0 + scol),
            (__attribute__((address_space(3))) void*)(As + srow * BK + scol), 16, 0, 0);
        __builtin_amdgcn_global_load_lds(
            (const __attribute__((address_space(1))) void*)(A + a_base + (long)(srow + 64) * K + k0 + scol),
            (__attribute__((address_space(3))) void*)(As + (srow + 64) * BK + scol), 16, 0, 0);
        __builtin_amdgcn_global_load_lds(
            (const __attribute__((address_space(1))) void*)(Bt + b_base + (long)srow * K + k0 + scol),
            (__attribute__((address_space(3))) void*)(Bs + srow * BK + scol), 16, 0, 0);
        __builtin_amdgcn_global_load_lds(
            (const __attribute__((address_space(1))) void*)(Bt + b_base + (long)(srow + 64) * K + k0 + scol),
            (__attribute__((address_space(3))) void*)(Bs + (srow + 64) * BK + scol), 16, 0, 0);
        __syncthreads();

        short8 a[4], b[4];
#pragma unroll
        for (int mi = 0; mi < 4; mi++)
            a[mi] = *(const short8*)(As + (wm * 64 + mi * 16 + lrow) * BK + lko);
#pragma unroll
        for (int nj = 0; nj < 4; nj++)
            b[nj] = *(const short8*)(Bs + (wn * 64 + nj * 16 + lrow) * BK + lko);
#pragma unroll
        for (int mi = 0; mi < 4; mi++)
#pragma unroll
            for (int nj = 0; nj < 4; nj++)
                acc[mi][nj] = __builtin_amdgcn_mfma_f32_16x16x32_bf16(
                    a[mi], b[nj], acc[mi][nj], 0, 0, 0);
        __syncthreads();
    }

    // epilogue: + bias, ReLU, store bf16
    // C/D layout (m89-verified): col = lane&15, row = (lane>>4)*4 + reg
#pragma unroll
    for (int mi = 0; mi < 4; mi++) {
        int row = bm * BM + wm * 64 + mi * 16 + (lane >> 4) * 4;
#pragma unroll
        for (int nj = 0; nj < 4; nj++) {
            int col = bn * BN + wn * 64 + nj * 16 + (lane & 15);
            float bv = bias[col];
#pragma unroll
            for (int r = 0; r < 4; r++) {
                float v = acc[mi][nj][r] + bv;
                v = fmaxf(v, 0.0f);
                H[(long)(row + r) * D_OUT + col] = f2bf(v);
            }
        }
    }
}

// ---------- 4. LayerNorm + mask-pack ----------
__global__ void ln_pack_kernel(const short* __restrict__ H,      // bf16 [32768][1024]
                               const int* __restrict__ mask,     // [512][64]
                               const float* __restrict__ ln_w,
                               const float* __restrict__ ln_b,
                               float* __restrict__ out) {        // [512][64][1024]
    int row = blockIdx.x;            // source row (b, n)
    int b = row >> 6, n = row & 63;
    int tid = threadIdx.x;
    int lane = tid & 63;
    int wave = tid >> 6;

    int mv = mask[(b << 6) | lane];
    unsigned long long bal = __ballot(mv != 0);
    if (!((bal >> n) & 1ull)) return;                    // padded row -> stays zero
    int dest = __popcll(bal & ((1ull << n) - 1ull));     // stable prefix position

    int base = tid * 4;                                  // 256 threads x 4 elems
    short4v hv = *(const short4v*)(H + (long)row * D_OUT + base);
    float v0 = bf2f(hv[0]), v1 = bf2f(hv[1]), v2 = bf2f(hv[2]), v3 = bf2f(hv[3]);

    float s  = v0 + v1 + v2 + v3;
    float s2 = v0 * v0 + v1 * v1 + v2 * v2 + v3 * v3;
#pragma unroll
    for (int off = 32; off > 0; off >>= 1) {
        s  += __shfl_xor(s, off);
        s2 += __shfl_xor(s2, off);
    }
    __shared__ float red[8];
    if (lane == 0) { red[wave] = s; red[wave + 4] = s2; }
    __syncthreads();
    float S  = red[0] + red[1] + red[2] + red[3];
    float S2 = red[4] + red[5] + red[6] + red[7];
    float mu   = S * (1.0f / D_OUT);
    float var  = S2 * (1.0f / D_OUT) - mu * mu;
    float rstd = rsqrtf(var + 1e-12f);

    float4 wv = *(const float4*)(ln_w + base);
    float4 bv = *(const float4*)(ln_b + base);
    float4 o;
    o.x = (v0 - mu) * rstd * wv.x + bv.x;
    o.y = (v1 - mu) * rstd * wv.y + bv.y;
    o.z = (v2 - mu) * rstd * wv.z + bv.z;
    o.w = (v3 - mu) * rstd * wv.w + bv.w;
    *(float4*)(out + (long)((b << 6) + dest) * D_OUT + base) = o;
}

// ---------- launch ----------
extern "C" void kernel_launch(void* const* d_in, const int* in_sizes, int n_in,
                              void* d_out, int out_size, void* d_ws, size_t ws_size,
                              hipStream_t stream) {
    const float* img  = (const float*)d_in[0];
    const int*   mask = (const int*)d_in[2];
    const float* W    = (const float*)d_in[4];
    const float* bias = (const float*)d_in[5];
    const float* lnw  = (const float*)d_in[6];
    const float* lnb  = (const float*)d_in[7];
    float* out = (float*)d_out;

    // scratch layout: d_out doubles as A_bf16 (exactly 128 MiB), consumed by
    // the GEMM before the memset+ln_pack rewrite it.
    short* Abf = (short*)d_out;                       // 32768*2048 bf16 = 128 MiB
    short* Bt  = (short*)d_ws;                        // 1024*2048 bf16  = 4 MiB
    short* H   = (short*)d_ws + (long)D_OUT * D_IN;   // 32768*1024 bf16 = 64 MiB

    cast_a_kernel<<<2048, 256, 0, stream>>>(img, Abf, M_ROWS * D_IN / 8);
    transpose_w_kernel<<<dim3(D_OUT / 32, D_IN / 32), 256, 0, stream>>>(W, Bt);
    gemm_bias_relu_kernel<<<(M_ROWS / BM) * (D_OUT / BN), 256, 0, stream>>>(Abf, Bt, bias, H);
    hipMemsetAsync(d_out, 0, (size_t)out_size * sizeof(float), stream);
    ln_pack_kernel<<<M_ROWS, 256, 0, stream>>>(H, mask, lnw, lnb, out);
}

// Round 2
// 287.314 us; speedup vs baseline: 1.0610x; 1.0610x over previous
//
#include <hip/hip_runtime.h>
#include <hip/hip_bf16.h>

// ---------- types ----------
typedef __attribute__((ext_vector_type(8))) short short8;   // 8 bf16 (4 VGPR)
typedef __attribute__((ext_vector_type(4))) short short4v;  // 4 bf16
typedef __attribute__((ext_vector_type(4))) float f32x4;

#define B_SZ   512
#define N_BOX  64
#define D_IN   2048
#define D_OUT  1024
#define M_ROWS (B_SZ * N_BOX)   // 32768

__device__ __forceinline__ short f2bf(float x) {
    union { __hip_bfloat16 h; short s; } u;
    u.h = __float2bfloat16(x);
    return u.s;
}
__device__ __forceinline__ float bf2f(short s) {
    union { short s; __hip_bfloat16 h; } u;
    u.s = s;
    return __bfloat162float(u.h);
}

// ---------- 1. cast img_feats f32 -> bf16 ----------
__global__ void cast_a_kernel(const float* __restrict__ in,
                              short* __restrict__ out, int n8) {
    int i = blockIdx.x * blockDim.x + threadIdx.x;
    int stride = gridDim.x * blockDim.x;
    for (int j = i; j < n8; j += stride) {
        long e = (long)j * 8;
        float4 v0 = *(const float4*)(in + e);
        float4 v1 = *(const float4*)(in + e + 4);
        short8 o;
        o[0] = f2bf(v0.x); o[1] = f2bf(v0.y); o[2] = f2bf(v0.z); o[3] = f2bf(v0.w);
        o[4] = f2bf(v1.x); o[5] = f2bf(v1.y); o[6] = f2bf(v1.z); o[7] = f2bf(v1.w);
        *(short8*)(out + e) = o;
    }
}

// ---------- 2. W [2048][1024] f32 -> Bt [1024][2048] bf16 ----------
__global__ void transpose_w_kernel(const float* __restrict__ W,
                                   short* __restrict__ Bt) {
    __shared__ float tile[32][33];
    int c0 = blockIdx.x * 32;
    int r0 = blockIdx.y * 32;
    int tc = threadIdx.x & 31;
    int tr = threadIdx.x >> 5;
#pragma unroll
    for (int i = 0; i < 32; i += 8)
        tile[tr + i][tc] = W[(long)(r0 + tr + i) * D_OUT + c0 + tc];
    __syncthreads();
#pragma unroll
    for (int i = 0; i < 32; i += 8)
        Bt[(long)(c0 + tr + i) * D_IN + r0 + tc] = f2bf(tile[tc][tr + i]);
}

// ---------- 3. GEMM: 256x256 tile, BK=64, 8-phase schedule ----------
// Both A [32768][2048] and Bt [1024][2048] are bf16 with K-stride 2048.
#define HALF_SHORTS 8192    // one half-tile: 128 rows x 64 k bf16 = 16 KB

// Stage one 128x64 half-tile: linear LDS dest (lane-ordered, required by
// global_load_lds) + inverse-swizzled global source (st_16x32: b5 ^= b9).
__device__ __forceinline__ void stage_half(const short* __restrict__ mat, long row0, int k0,
                                           short* lds, int tid) {
#pragma unroll
    for (int j = 0; j < 2; ++j) {
        int d = j * 8192 + tid * 16;            // byte offset in 16 KB half
        int s = d ^ (((d >> 9) & 1) << 5);      // involution
        int row = s >> 7;                        // 0..127
        int ke  = (s & 127) >> 1;                // element 0..63
        __builtin_amdgcn_global_load_lds(
            (const __attribute__((address_space(1))) void*)(mat + (row0 + row) * D_IN + k0 + ke),
            (__attribute__((address_space(3))) void*)((char*)lds + d), 16, 0, 0);
    }
}

// swizzled ds_read of one 16B MFMA fragment from a half-tile
__device__ __forceinline__ short8 ld_frag(const short* lds, int rowh, int kb) {
    int d = rowh * 128 + kb;
    d ^= ((d >> 9) & 1) << 5;
    return *(const short8*)((const char*)lds + d);
}

#define BAR()   __builtin_amdgcn_s_barrier()
#define LGKM0() do { asm volatile("s_waitcnt lgkmcnt(0)" ::: "memory"); \
                     __builtin_amdgcn_sched_barrier(0); } while (0)
#define VM6()   do { asm volatile("s_waitcnt vmcnt(6)" ::: "memory");  \
                     __builtin_amdgcn_sched_barrier(0); } while (0)

__global__ __launch_bounds__(512, 2)
void gemm256_kernel(const short* __restrict__ A, const short* __restrict__ Bt,
                    const float* __restrict__ bias, short* __restrict__ H) {
    __shared__ short As[4 * HALF_SHORTS];   // [dbuf][half] 64 KiB
    __shared__ short Bs[4 * HALF_SHORTS];   // 64 KiB

    // XCD-bijective swizzle (512 % 8 == 0): each XCD gets 64 consecutive lids,
    // bn fastest so all 4 B-panels + a 16-tile A stripe stay L2/LLC-hot.
    int bid = blockIdx.x;
    int lid = (bid & 7) * 64 + (bid >> 3);
    int bn = lid & 3;      // 0..3
    int bm = lid >> 2;     // 0..127

    int tid  = threadIdx.x;
    int lane = tid & 63;
    int wave = tid >> 6;
    int wm = wave >> 2;            // 0..1  -> A half
    int wn = wave & 3;             // 0..3
    int bh = wn >> 1;              // B half
    int lrow = lane & 15;
    int lkb  = (lane >> 4) * 16;   // fragment k byte offset

    const long arow0 = (long)bm * 256;
    const long brow0 = (long)bn * 256;

    f32x4 acc[8][4];
#pragma unroll
    for (int i = 0; i < 8; ++i)
#pragma unroll
        for (int j = 0; j < 4; ++j) acc[i][j] = (f32x4)0.0f;

    const int nt = D_IN / 64;   // 32 K-tiles

    // prologue: tile0 {B0,B1,A0,A1} + tile1 {B0,B1,A0} = 7 half-tiles (14 loads)
    stage_half(Bt, brow0,       0,  Bs + 0 * HALF_SHORTS, tid);
    stage_half(Bt, brow0 + 128, 0,  Bs + 1 * HALF_SHORTS, tid);
    stage_half(A,  arow0,       0,  As + 0 * HALF_SHORTS, tid);
    stage_half(A,  arow0 + 128, 0,  As + 1 * HALF_SHORTS, tid);
    stage_half(Bt, brow0,       64, Bs + 2 * HALF_SHORTS, tid);
    stage_half(Bt, brow0 + 128, 64, Bs + 3 * HALF_SHORTS, tid);
    stage_half(A,  arow0,       64, As + 2 * HALF_SHORTS, tid);
    VM6();                        // tile0 complete; tile1's 3 halves in flight
    BAR();

    short8 a[2][4], b[2][4];

#pragma unroll 1
    for (int t = 0; t < nt; ++t) {
        int buf  = t & 1;
        int nbuf = buf ^ 1;
        const short* Ah = As + (buf * 2 + wm) * HALF_SHORTS;
        const short* Bh = Bs + (buf * 2 + bh) * HALF_SHORTS;
        short* As_buf = As + buf * 2 * HALF_SHORTS;
        short* Bs_buf = Bs + buf * 2 * HALF_SHORTS;
        int k1 = ((t + 1) & (nt - 1)) * 64;   // wrapped at tail (harmless data)
        int k2 = ((t + 2) & (nt - 1)) * 64;

        // ---- P1: ds-read A[M0] + all B (16x b128); stage (t+1, A1); MFMA M0N0
#pragma unroll
        for (int ks = 0; ks < 2; ++ks) {
#pragma unroll
            for (int mi = 0; mi < 4; ++mi)
                a[ks][mi] = ld_frag(Ah, mi * 16 + lrow, ks * 64 + lkb);
#pragma unroll
            for (int nj = 0; nj < 4; ++nj)
                b[ks][nj] = ld_frag(Bh, (wn & 1) * 64 + nj * 16 + lrow, ks * 64 + lkb);
        }
        stage_half(A, arow0 + 128, k1, As + (nbuf * 2 + 1) * HALF_SHORTS, tid);
        BAR();
        LGKM0();
        __builtin_amdgcn_s_setprio(1);
#pragma unroll
        for (int mi = 0; mi < 4; ++mi)
#pragma unroll
            for (int nj = 0; nj < 2; ++nj)
#pragma unroll
                for (int ks = 0; ks < 2; ++ks)
                    acc[mi][nj] = __builtin_amdgcn_mfma_f32_16x16x32_bf16(
                        a[ks][mi], b[ks][nj], acc[mi][nj], 0, 0, 0);
        __builtin_amdgcn_s_setprio(0);
        BAR();

        // ---- P2: stage (t+2, B0); MFMA M0N1    (B fully consumed in P1)
        stage_half(Bt, brow0, k2, Bs_buf + 0 * HALF_SHORTS, tid);
        BAR();
        __builtin_amdgcn_s_setprio(1);
#pragma unroll
        for (int mi = 0; mi < 4; ++mi)
#pragma unroll
            for (int nj = 2; nj < 4; ++nj)
#pragma unroll
                for (int ks = 0; ks < 2; ++ks)
                    acc[mi][nj] = __builtin_amdgcn_mfma_f32_16x16x32_bf16(
                        a[ks][mi], b[ks][nj], acc[mi][nj], 0, 0, 0);
        __builtin_amdgcn_s_setprio(0);
        BAR();

        // ---- P3: ds-read A[M1] (8x b128); stage (t+2, B1); MFMA M1N0
#pragma unroll
        for (int ks = 0; ks < 2; ++ks)
#pragma unroll
            for (int mi = 0; mi < 4; ++mi)
                a[ks][mi] = ld_frag(Ah, 64 + mi * 16 + lrow, ks * 64 + lkb);
        stage_half(Bt, brow0 + 128, k2, Bs_buf + 1 * HALF_SHORTS, tid);
        BAR();
        LGKM0();
        __builtin_amdgcn_s_setprio(1);
#pragma unroll
        for (int mi = 0; mi < 4; ++mi)
#pragma unroll
            for (int nj = 0; nj < 2; ++nj)
#pragma unroll
                for (int ks = 0; ks < 2; ++ks)
                    acc[4 + mi][nj] = __builtin_amdgcn_mfma_f32_16x16x32_bf16(
                        a[ks][mi], b[ks][nj], acc[4 + mi][nj], 0, 0, 0);
        __builtin_amdgcn_s_setprio(0);
        BAR();

        // ---- P4: stage (t+2, A0); MFMA M1N1; counted vmcnt (never 0)
        stage_half(A, arow0, k2, As_buf + 0 * HALF_SHORTS, tid);
        BAR();
        __builtin_amdgcn_s_setprio(1);
#pragma unroll
        for (int mi = 0; mi < 4; ++mi)
#pragma unroll
            for (int nj = 2; nj < 4; ++nj)
#pragma unroll
                for (int ks = 0; ks < 2; ++ks)
                    acc[4 + mi][nj] = __builtin_amdgcn_mfma_f32_16x16x32_bf16(
                        a[ks][mi], b[ks][nj], acc[4 + mi][nj], 0, 0, 0);
        __builtin_amdgcn_s_setprio(0);
        VM6();                      // tile t+1 guaranteed staged; 3 halves in flight
        BAR();
    }

    // ---- epilogue: + bias, ReLU, store bf16.  C/D: col=lane&15, row=(lane>>4)*4+reg
    float bb[4];
#pragma unroll
    for (int nj = 0; nj < 4; ++nj)
        bb[nj] = bias[bn * 256 + wn * 64 + nj * 16 + lrow];
#pragma unroll
    for (int mi = 0; mi < 8; ++mi) {
        long row = arow0 + wm * 128 + mi * 16 + (lane >> 4) * 4;
#pragma unroll
        for (int nj = 0; nj < 4; ++nj) {
            int col = bn * 256 + wn * 64 + nj * 16 + lrow;
#pragma unroll
            for (int r = 0; r < 4; ++r) {
                float v = fmaxf(acc[mi][nj][r] + bb[nj], 0.0f);
                H[(row + r) * D_OUT + col] = f2bf(v);
            }
        }
    }
}

// ---------- 4. LayerNorm + mask-pack ----------
__global__ void ln_pack_kernel(const short* __restrict__ H,      // bf16 [32768][1024]
                               const int* __restrict__ mask,     // [512][64]
                               const float* __restrict__ ln_w,
                               const float* __restrict__ ln_b,
                               float* __restrict__ out) {        // [512][64][1024]
    int row = blockIdx.x;
    int b = row >> 6, n = row & 63;
    int tid = threadIdx.x;
    int lane = tid & 63;
    int wave = tid >> 6;

    int mv = mask[(b << 6) | lane];
    unsigned long long bal = __ballot(mv != 0);
    if (!((bal >> n) & 1ull)) return;
    int dest = __popcll(bal & ((1ull << n) - 1ull));

    int base = tid * 4;
    short4v hv = *(const short4v*)(H + (long)row * D_OUT + base);
    float v0 = bf2f(hv[0]), v1 = bf2f(hv[1]), v2 = bf2f(hv[2]), v3 = bf2f(hv[3]);

    float s  = v0 + v1 + v2 + v3;
    float s2 = v0 * v0 + v1 * v1 + v2 * v2 + v3 * v3;
#pragma unroll
    for (int off = 32; off > 0; off >>= 1) {
        s  += __shfl_xor(s, off);
        s2 += __shfl_xor(s2, off);
    }
    __shared__ float red[8];
    if (lane == 0) { red[wave] = s; red[wave + 4] = s2; }
    __syncthreads();
    float S  = red[0] + red[1] + red[2] + red[3];
    float S2 = red[4] + red[5] + red[6] + red[7];
    float mu   = S * (1.0f / D_OUT);
    float var  = S2 * (1.0f / D_OUT) - mu * mu;
    float rstd = rsqrtf(var + 1e-12f);

    float4 wv = *(const float4*)(ln_w + base);
    float4 bv = *(const float4*)(ln_b + base);
    float4 o;
    o.x = (v0 - mu) * rstd * wv.x + bv.x;
    o.y = (v1 - mu) * rstd * wv.y + bv.y;
    o.z = (v2 - mu) * rstd * wv.z + bv.z;
    o.w = (v3 - mu) * rstd * wv.w + bv.w;
    *(float4*)(out + (long)((b << 6) + dest) * D_OUT + base) = o;
}

// ---------- launch ----------
extern "C" void kernel_launch(void* const* d_in, const int* in_sizes, int n_in,
                              void* d_out, int out_size, void* d_ws, size_t ws_size,
                              hipStream_t stream) {
    const float* img  = (const float*)d_in[0];
    const int*   mask = (const int*)d_in[2];
    const float* W    = (const float*)d_in[4];
    const float* bias = (const float*)d_in[5];
    const float* lnw  = (const float*)d_in[6];
    const float* lnb  = (const float*)d_in[7];
    float* out = (float*)d_out;

    // d_out doubles as A_bf16 scratch (exactly 128 MiB), consumed by the GEMM
    // before the memset + ln_pack rewrite it.
    short* Abf = (short*)d_out;                       // 128 MiB
    short* Bt  = (short*)d_ws;                        // 4 MiB
    short* H   = (short*)d_ws + (long)D_OUT * D_IN;   // 64 MiB

    cast_a_kernel<<<2048, 256, 0, stream>>>(img, Abf, M_ROWS * D_IN / 8);
    transpose_w_kernel<<<dim3(D_OUT / 32, D_IN / 32), 256, 0, stream>>>(W, Bt);
    gemm256_kernel<<<(M_ROWS / 256) * (D_OUT / 256), 512, 0, stream>>>(Abf, Bt, bias, H);
    hipMemsetAsync(d_out, 0, (size_t)out_size * sizeof(float), stream);
    ln_pack_kernel<<<M_ROWS, 256, 0, stream>>>(H, mask, lnw, lnb, out);
}

// Round 3
// 263.294 us; speedup vs baseline: 1.1578x; 1.0912x over previous
//
#include <hip/hip_runtime.h>
#include <hip/hip_bf16.h>

// ---------- types ----------
typedef __attribute__((ext_vector_type(8))) short short8;   // 8 bf16 (4 VGPR)
typedef __attribute__((ext_vector_type(4))) short short4v;  // 4 bf16
typedef __attribute__((ext_vector_type(4))) float f32x4;

#define B_SZ   512
#define N_BOX  64
#define D_IN   2048
#define D_OUT  1024
#define M_ROWS (B_SZ * N_BOX)   // 32768

__device__ __forceinline__ short f2bf(float x) {
    union { __hip_bfloat16 h; short s; } u;
    u.h = __float2bfloat16(x);
    return u.s;
}
__device__ __forceinline__ float bf2f(short s) {
    union { short s; __hip_bfloat16 h; } u;
    u.s = s;
    return __bfloat162float(u.h);
}

// ---------- 1. cast img_feats f32 -> bf16 ----------
__global__ void cast_a_kernel(const float* __restrict__ in,
                              short* __restrict__ out, int n8) {
    int i = blockIdx.x * blockDim.x + threadIdx.x;
    int stride = gridDim.x * blockDim.x;
    for (int j = i; j < n8; j += stride) {
        long e = (long)j * 8;
        float4 v0 = *(const float4*)(in + e);
        float4 v1 = *(const float4*)(in + e + 4);
        short8 o;
        o[0] = f2bf(v0.x); o[1] = f2bf(v0.y); o[2] = f2bf(v0.z); o[3] = f2bf(v0.w);
        o[4] = f2bf(v1.x); o[5] = f2bf(v1.y); o[6] = f2bf(v1.z); o[7] = f2bf(v1.w);
        *(short8*)(out + e) = o;
    }
}

// ---------- 2. W [2048][1024] f32 -> Bt [1024][2048] bf16 ----------
__global__ void transpose_w_kernel(const float* __restrict__ W,
                                   short* __restrict__ Bt) {
    __shared__ float tile[32][33];
    int c0 = blockIdx.x * 32;
    int r0 = blockIdx.y * 32;
    int tc = threadIdx.x & 31;
    int tr = threadIdx.x >> 5;
#pragma unroll
    for (int i = 0; i < 32; i += 8)
        tile[tr + i][tc] = W[(long)(r0 + tr + i) * D_OUT + c0 + tc];
    __syncthreads();
#pragma unroll
    for (int i = 0; i < 32; i += 8)
        Bt[(long)(c0 + tr + i) * D_IN + r0 + tc] = f2bf(tile[tc][tr + i]);
}

// ---------- 3. GEMM: 256x256 tile, BK=64, 8-phase schedule ----------
// Both A [32768][2048] and Bt [1024][2048] are bf16 with K-stride 2048.
#define HALF_SHORTS 8192    // one half-tile: 128 rows x 64 k bf16 = 16 KB

// Swizzle: physical = logical ^ ((row&7)<<4).  Rows are 128 B; a fragment
// read puts 16 lanes on 16 rows at one 16B column -> unswizzled 16-way bank
// conflict. 3-bit row XOR spreads 8 rows over all 32 banks (2-way = free).
// Involution (bits >=7 untouched), applied on BOTH sides (rule #21).

// Stage one 128x64 half-tile: linear LDS dest (lane-ordered, required by
// global_load_lds) + inverse-swizzled global source.
__device__ __forceinline__ void stage_half(const short* __restrict__ mat, long row0, int k0,
                                           short* lds, int tid) {
#pragma unroll
    for (int j = 0; j < 2; ++j) {
        int d = j * 8192 + tid * 16;            // physical byte offset in 16 KB half
        int s = d ^ (((d >> 7) & 7) << 4);      // logical byte offset
        int row = s >> 7;                        // 0..127
        int ke  = (s & 127) >> 1;                // element 0..63
        __builtin_amdgcn_global_load_lds(
            (const __attribute__((address_space(1))) void*)(mat + (row0 + row) * D_IN + k0 + ke),
            (__attribute__((address_space(3))) void*)((char*)lds + d), 16, 0, 0);
    }
}

// swizzled ds_read of one 16B MFMA fragment from a half-tile
__device__ __forceinline__ short8 ld_frag(const short* lds, int rowh, int kb) {
    int d = (rowh * 128 + kb) ^ ((rowh & 7) << 4);
    return *(const short8*)((const char*)lds + d);
}

#define BAR()   __builtin_amdgcn_s_barrier()
#define LGKM0() do { asm volatile("s_waitcnt lgkmcnt(0)" ::: "memory"); \
                     __builtin_amdgcn_sched_barrier(0); } while (0)
#define VM6()   do { asm volatile("s_waitcnt vmcnt(6)" ::: "memory");  \
                     __builtin_amdgcn_sched_barrier(0); } while (0)

__global__ __launch_bounds__(512, 2)
void gemm256_kernel(const short* __restrict__ A, const short* __restrict__ Bt,
                    const float* __restrict__ bias, short* __restrict__ H) {
    __shared__ short As[4 * HALF_SHORTS];   // [dbuf][half] 64 KiB
    __shared__ short Bs[4 * HALF_SHORTS];   // 64 KiB

    // XCD-bijective swizzle (512 % 8 == 0)
    int bid = blockIdx.x;
    int lid = (bid & 7) * 64 + (bid >> 3);
    int bn = lid & 3;      // 0..3
    int bm = lid >> 2;     // 0..127

    int tid  = threadIdx.x;
    int lane = tid & 63;
    int wave = tid >> 6;
    int wm = wave >> 2;            // 0..1  -> A half
    int wn = wave & 3;             // 0..3
    int bh = wn >> 1;              // B half
    int lrow = lane & 15;
    int lkb  = (lane >> 4) * 16;   // fragment k byte offset

    const long arow0 = (long)bm * 256;
    const long brow0 = (long)bn * 256;

    f32x4 acc[8][4];
#pragma unroll
    for (int i = 0; i < 8; ++i)
#pragma unroll
        for (int j = 0; j < 4; ++j) acc[i][j] = (f32x4)0.0f;

    const int nt = D_IN / 64;   // 32 K-tiles

    // prologue: tile0 {B0,B1,A0,A1} + tile1 {B0,B1,A0} = 7 half-tiles (14 loads)
    stage_half(Bt, brow0,       0,  Bs + 0 * HALF_SHORTS, tid);
    stage_half(Bt, brow0 + 128, 0,  Bs + 1 * HALF_SHORTS, tid);
    stage_half(A,  arow0,       0,  As + 0 * HALF_SHORTS, tid);
    stage_half(A,  arow0 + 128, 0,  As + 1 * HALF_SHORTS, tid);
    stage_half(Bt, brow0,       64, Bs + 2 * HALF_SHORTS, tid);
    stage_half(Bt, brow0 + 128, 64, Bs + 3 * HALF_SHORTS, tid);
    stage_half(A,  arow0,       64, As + 2 * HALF_SHORTS, tid);
    VM6();                        // tile0 complete; tile1's 3 halves in flight
    BAR();

    short8 a[2][4], b[2][4];

#pragma unroll 1
    for (int t = 0; t < nt; ++t) {
        int buf  = t & 1;
        int nbuf = buf ^ 1;
        const short* Ah = As + (buf * 2 + wm) * HALF_SHORTS;
        const short* Bh = Bs + (buf * 2 + bh) * HALF_SHORTS;
        short* As_buf = As + buf * 2 * HALF_SHORTS;
        short* Bs_buf = Bs + buf * 2 * HALF_SHORTS;
        int k1 = ((t + 1) & (nt - 1)) * 64;   // wrapped at tail (harmless data)
        int k2 = ((t + 2) & (nt - 1)) * 64;

        // ---- P1: ds-read A[M0] + all B (16x b128); stage (t+1, A1); MFMA M0N0
#pragma unroll
        for (int ks = 0; ks < 2; ++ks) {
#pragma unroll
            for (int mi = 0; mi < 4; ++mi)
                a[ks][mi] = ld_frag(Ah, mi * 16 + lrow, ks * 64 + lkb);
#pragma unroll
            for (int nj = 0; nj < 4; ++nj)
                b[ks][nj] = ld_frag(Bh, (wn & 1) * 64 + nj * 16 + lrow, ks * 64 + lkb);
        }
        stage_half(A, arow0 + 128, k1, As + (nbuf * 2 + 1) * HALF_SHORTS, tid);
        BAR();
        LGKM0();
        __builtin_amdgcn_s_setprio(1);
#pragma unroll
        for (int mi = 0; mi < 4; ++mi)
#pragma unroll
            for (int nj = 0; nj < 2; ++nj)
#pragma unroll
                for (int ks = 0; ks < 2; ++ks)
                    acc[mi][nj] = __builtin_amdgcn_mfma_f32_16x16x32_bf16(
                        a[ks][mi], b[ks][nj], acc[mi][nj], 0, 0, 0);
        __builtin_amdgcn_s_setprio(0);
        BAR();

        // ---- P2: stage (t+2, B0); MFMA M0N1    (B fully consumed in P1)
        stage_half(Bt, brow0, k2, Bs_buf + 0 * HALF_SHORTS, tid);
        BAR();
        __builtin_amdgcn_s_setprio(1);
#pragma unroll
        for (int mi = 0; mi < 4; ++mi)
#pragma unroll
            for (int nj = 2; nj < 4; ++nj)
#pragma unroll
                for (int ks = 0; ks < 2; ++ks)
                    acc[mi][nj] = __builtin_amdgcn_mfma_f32_16x16x32_bf16(
                        a[ks][mi], b[ks][nj], acc[mi][nj], 0, 0, 0);
        __builtin_amdgcn_s_setprio(0);
        BAR();

        // ---- P3: ds-read A[M1] (8x b128); stage (t+2, B1); MFMA M1N0
#pragma unroll
        for (int ks = 0; ks < 2; ++ks)
#pragma unroll
            for (int mi = 0; mi < 4; ++mi)
                a[ks][mi] = ld_frag(Ah, 64 + mi * 16 + lrow, ks * 64 + lkb);
        stage_half(Bt, brow0 + 128, k2, Bs_buf + 1 * HALF_SHORTS, tid);
        BAR();
        LGKM0();
        __builtin_amdgcn_s_setprio(1);
#pragma unroll
        for (int mi = 0; mi < 4; ++mi)
#pragma unroll
            for (int nj = 0; nj < 2; ++nj)
#pragma unroll
                for (int ks = 0; ks < 2; ++ks)
                    acc[4 + mi][nj] = __builtin_amdgcn_mfma_f32_16x16x32_bf16(
                        a[ks][mi], b[ks][nj], acc[4 + mi][nj], 0, 0, 0);
        __builtin_amdgcn_s_setprio(0);
        BAR();

        // ---- P4: stage (t+2, A0); MFMA M1N1; counted vmcnt (never 0)
        stage_half(A, arow0, k2, As_buf + 0 * HALF_SHORTS, tid);
        BAR();
        __builtin_amdgcn_s_setprio(1);
#pragma unroll
        for (int mi = 0; mi < 4; ++mi)
#pragma unroll
            for (int nj = 2; nj < 4; ++nj)
#pragma unroll
                for (int ks = 0; ks < 2; ++ks)
                    acc[4 + mi][nj] = __builtin_amdgcn_mfma_f32_16x16x32_bf16(
                        a[ks][mi], b[ks][nj], acc[4 + mi][nj], 0, 0, 0);
        __builtin_amdgcn_s_setprio(0);
        VM6();                      // tile t+1 guaranteed staged; 3 halves in flight
        BAR();
    }

    // ---- epilogue: + bias, ReLU, store bf16.  C/D: col=lane&15, row=(lane>>4)*4+reg
    float bb[4];
#pragma unroll
    for (int nj = 0; nj < 4; ++nj)
        bb[nj] = bias[bn * 256 + wn * 64 + nj * 16 + lrow];
#pragma unroll
    for (int mi = 0; mi < 8; ++mi) {
        long row = arow0 + wm * 128 + mi * 16 + (lane >> 4) * 4;
#pragma unroll
        for (int nj = 0; nj < 4; ++nj) {
            int col = bn * 256 + wn * 64 + nj * 16 + lrow;
#pragma unroll
            for (int r = 0; r < 4; ++r) {
                float v = fmaxf(acc[mi][nj][r] + bb[nj], 0.0f);
                H[(row + r) * D_OUT + col] = f2bf(v);
            }
        }
    }
}

// ---------- 4. LayerNorm + mask-pack (dest-indexed; writes EVERY output row,
//              zeros for the padded tail -> no separate memset needed) ----------
__global__ void ln_pack_kernel(const short* __restrict__ H,      // bf16 [32768][1024]
                               const int* __restrict__ mask,     // [512][64]
                               const float* __restrict__ ln_w,
                               const float* __restrict__ ln_b,
                               float* __restrict__ out) {        // [512][64][1024]
    int drow = blockIdx.x;           // destination row (b, j)
    int b = drow >> 6, j = drow & 63;
    int tid = threadIdx.x;
    int lane = tid & 63;
    int wave = tid >> 6;
    int base = tid * 4;              // 256 threads x 4 elems

    int mv = mask[(b << 6) | lane];
    unsigned long long bal = __ballot(mv != 0);
    int cnt = __popcll(bal);

    float4 o = make_float4(0.f, 0.f, 0.f, 0.f);
    if (j < cnt) {                   // block-uniform branch
        int pre = __popcll(bal & ((1ull << lane) - 1ull));
        unsigned long long sel = __ballot(mv != 0 && pre == j);
        int srcn = (int)__builtin_ctzll(sel);        // j-th valid source index
        long row = (long)((b << 6) | srcn);

        short4v hv = *(const short4v*)(H + row * D_OUT + base);
        float v0 = bf2f(hv[0]), v1 = bf2f(hv[1]), v2 = bf2f(hv[2]), v3 = bf2f(hv[3]);

        float s  = v0 + v1 + v2 + v3;
        float s2 = v0 * v0 + v1 * v1 + v2 * v2 + v3 * v3;
#pragma unroll
        for (int off = 32; off > 0; off >>= 1) {
            s  += __shfl_xor(s, off);
            s2 += __shfl_xor(s2, off);
        }
        __shared__ float red[8];
        if (lane == 0) { red[wave] = s; red[wave + 4] = s2; }
        __syncthreads();
        float S  = red[0] + red[1] + red[2] + red[3];
        float S2 = red[4] + red[5] + red[6] + red[7];
        float mu   = S * (1.0f / D_OUT);
        float var  = S2 * (1.0f / D_OUT) - mu * mu;
        float rstd = rsqrtf(var + 1e-12f);

        float4 wv = *(const float4*)(ln_w + base);
        float4 bv = *(const float4*)(ln_b + base);
        o.x = (v0 - mu) * rstd * wv.x + bv.x;
        o.y = (v1 - mu) * rstd * wv.y + bv.y;
        o.z = (v2 - mu) * rstd * wv.z + bv.z;
        o.w = (v3 - mu) * rstd * wv.w + bv.w;
    }
    *(float4*)(out + (long)drow * D_OUT + base) = o;
}

// ---------- launch ----------
extern "C" void kernel_launch(void* const* d_in, const int* in_sizes, int n_in,
                              void* d_out, int out_size, void* d_ws, size_t ws_size,
                              hipStream_t stream) {
    const float* img  = (const float*)d_in[0];
    const int*   mask = (const int*)d_in[2];
    const float* W    = (const float*)d_in[4];
    const float* bias = (const float*)d_in[5];
    const float* lnw  = (const float*)d_in[6];
    const float* lnb  = (const float*)d_in[7];
    float* out = (float*)d_out;

    // d_out doubles as A_bf16 scratch (exactly 128 MiB), consumed by the GEMM,
    // then fully overwritten by the dest-indexed ln_pack.
    short* Abf = (short*)d_out;                       // 128 MiB
    short* Bt  = (short*)d_ws;                        // 4 MiB
    short* H   = (short*)d_ws + (long)D_OUT * D_IN;   // 64 MiB

    cast_a_kernel<<<2048, 256, 0, stream>>>(img, Abf, M_ROWS * D_IN / 8);
    transpose_w_kernel<<<dim3(D_OUT / 32, D_IN / 32), 256, 0, stream>>>(W, Bt);
    gemm256_kernel<<<(M_ROWS / 256) * (D_OUT / 256), 512, 0, stream>>>(Abf, Bt, bias, H);
    ln_pack_kernel<<<M_ROWS, 256, 0, stream>>>(H, mask, lnw, lnb, out);
}

// Round 4
// 228.929 us; speedup vs baseline: 1.3316x; 1.1501x over previous
//
#include <hip/hip_runtime.h>
#include <hip/hip_bf16.h>

// ---------- types ----------
typedef __attribute__((ext_vector_type(8))) short short8;   // 8 bf16 (4 VGPR)
typedef __attribute__((ext_vector_type(4))) short short4v;  // 4 bf16
typedef __attribute__((ext_vector_type(4))) float f32x4;

#define B_SZ   512
#define N_BOX  64
#define D_IN   2048
#define D_OUT  1024
#define M_ROWS (B_SZ * N_BOX)   // 32768

__device__ __forceinline__ short f2bf(float x) {
    union { __hip_bfloat16 h; short s; } u;
    u.h = __float2bfloat16(x);
    return u.s;
}
__device__ __forceinline__ float bf2f(short s) {
    union { short s; __hip_bfloat16 h; } u;
    u.s = s;
    return __bfloat162float(u.h);
}

// ---------- 1. cast img_feats f32 -> bf16 ----------
__global__ void cast_a_kernel(const float* __restrict__ in,
                              short* __restrict__ out, int n8) {
    int i = blockIdx.x * blockDim.x + threadIdx.x;
    int stride = gridDim.x * blockDim.x;
    for (int j = i; j < n8; j += stride) {
        long e = (long)j * 8;
        float4 v0 = *(const float4*)(in + e);
        float4 v1 = *(const float4*)(in + e + 4);
        short8 o;
        o[0] = f2bf(v0.x); o[1] = f2bf(v0.y); o[2] = f2bf(v0.z); o[3] = f2bf(v0.w);
        o[4] = f2bf(v1.x); o[5] = f2bf(v1.y); o[6] = f2bf(v1.z); o[7] = f2bf(v1.w);
        *(short8*)(out + e) = o;
    }
}

// ---------- 2. W [2048][1024] f32 -> Bt [1024][2048] bf16 ----------
__global__ void transpose_w_kernel(const float* __restrict__ W,
                                   short* __restrict__ Bt) {
    __shared__ float tile[32][33];
    int c0 = blockIdx.x * 32;
    int r0 = blockIdx.y * 32;
    int tc = threadIdx.x & 31;
    int tr = threadIdx.x >> 5;
#pragma unroll
    for (int i = 0; i < 32; i += 8)
        tile[tr + i][tc] = W[(long)(r0 + tr + i) * D_OUT + c0 + tc];
    __syncthreads();
#pragma unroll
    for (int i = 0; i < 32; i += 8)
        Bt[(long)(c0 + tr + i) * D_IN + r0 + tc] = f2bf(tile[tc][tr + i]);
}

// ---------- 3. GEMM: 256x256, BK=64, 4-phase lookahead schedule ----------
// LDS map (131072 B): A at 0 (buf b at b*32768, half h at h*16384),
//                     B at 65536 (same sub-layout).
// Swizzle (both sides): phys = logical ^ ((row&7)<<4) within a 16 KB half.
#define HALF_BYTES 16384

__device__ __forceinline__ void stage_half(const short* __restrict__ mat, long row0, int k0,
                                           char* ldsbase, int tid) {
#pragma unroll
    for (int j = 0; j < 2; ++j) {
        int d = j * 8192 + tid * 16;            // physical byte offset (linear dest)
        int s = d ^ (((d >> 7) & 7) << 4);      // logical byte offset
        int row = s >> 7;                        // 0..127
        int ke  = (s & 127) >> 1;                // element 0..63
        __builtin_amdgcn_global_load_lds(
            (const __attribute__((address_space(1))) void*)(mat + (row0 + row) * D_IN + k0 + ke),
            (__attribute__((address_space(3))) void*)(ldsbase + d), 16, 0, 0);
    }
}

#define BAR()    __builtin_amdgcn_s_barrier()
#define SB0()    __builtin_amdgcn_sched_barrier(0)
#define LGKM(n)  do { asm volatile("s_waitcnt lgkmcnt(" #n ")" ::: "memory"); SB0(); } while (0)
#define VMW(n)   do { asm volatile("s_waitcnt vmcnt(" #n ")" ::: "memory"); SB0(); } while (0)

__global__ __launch_bounds__(512, 2)
void gemm256_kernel(const short* __restrict__ A, const short* __restrict__ Bt,
                    const float* __restrict__ bias, short* __restrict__ H) {
    __shared__ char LDS[131072];

    // XCD-bijective swizzle (512 % 8 == 0)
    int bid = blockIdx.x;
    int lid = (bid & 7) * 64 + (bid >> 3);
    int bn = lid & 3;      // 0..3
    int bm = lid >> 2;     // 0..127

    int tid  = threadIdx.x;
    int lane = tid & 63;
    int wave = tid >> 6;
    int wm = wave >> 2;            // A half
    int wn = wave & 3;
    int bh = wn >> 1;              // B half
    int lrow = lane & 15;
    int lkb  = (lane >> 4) * 16;

    // Per-lane swizzled fragment bases (XOR folded in; +mi*2048/+8192/+nj*2048
    // offsets only touch bits >=11, never the XOR'd bits 4..6).
    int swz = (lrow & 7) << 4;
    int la0 = (lrow * 128 + lkb) ^ swz;          // ks=0
    int la1 = (lrow * 128 + 64 + lkb) ^ swz;     // ks=1
    int aO0 = wm * HALF_BYTES + la0;
    int aO1 = wm * HALF_BYTES + la1;
    int bO0 = 65536 + bh * HALF_BYTES + (wn & 1) * 8192 + la0;
    int bO1 = 65536 + bh * HALF_BYTES + (wn & 1) * 8192 + la1;

    const long arow0 = (long)bm * 256;
    const long brow0 = (long)bn * 256;

    f32x4 acc[8][4];
#pragma unroll
    for (int i = 0; i < 8; ++i)
#pragma unroll
        for (int j = 0; j < 4; ++j) acc[i][j] = (f32x4)0.0f;

    const int nt = D_IN / 64;   // 32

#define RD(off) (*(const short8*)(LDS + (off)))

    // ---- prologue: stage tile0 fully + B0,B1,A0 of tile1 (A1(1) staged in P1(0))
    stage_half(Bt, brow0,       0,  LDS + 65536,                 tid);  // B0(0)
    stage_half(Bt, brow0 + 128, 0,  LDS + 65536 + HALF_BYTES,    tid);  // B1(0)
    stage_half(A,  arow0,       0,  LDS,                         tid);  // A0(0)
    stage_half(A,  arow0 + 128, 0,  LDS + HALF_BYTES,            tid);  // A1(0)
    stage_half(Bt, brow0,       64, LDS + 65536 + 32768,             tid);  // B0(1)
    stage_half(Bt, brow0 + 128, 64, LDS + 65536 + 32768 + HALF_BYTES, tid);  // B1(1)
    stage_half(A,  arow0,       64, LDS + 32768,                 tid);  // A0(1)
    VMW(6);                       // tile0 complete; tile1's 3 halves in flight
    BAR(); SB0();

    short8 aC[2][4], aN[2][4], bN0[2][2], bN1[2][2];
    // preload tile0 P1 operands: A-M0 + B-N0  (12 reads, confirmed at P1's LGKM)
#pragma unroll
    for (int mi = 0; mi < 4; ++mi) { aC[0][mi] = RD(aO0 + mi * 2048); aC[1][mi] = RD(aO1 + mi * 2048); }
#pragma unroll
    for (int j = 0; j < 2; ++j)    { bN0[0][j] = RD(bO0 + j * 2048); bN0[1][j] = RD(bO1 + j * 2048); }

#pragma unroll 1
    for (int t = 0; t < nt; ++t) {
        int bufo  = (t & 1) * 32768;
        int nbufo = bufo ^ 32768;
        int k1 = ((t + 1) & (nt - 1)) * 64;
        int k2 = ((t + 2) & (nt - 1)) * 64;

        // ---- P1: read bN1(t); stage A1(t+1); MFMA M0N0 (aC x bN0)
#pragma unroll
        for (int j = 0; j < 2; ++j) {
            bN1[0][j] = RD(bufo + bO0 + (2 + j) * 2048);
            bN1[1][j] = RD(bufo + bO1 + (2 + j) * 2048);
        }
        stage_half(A, arow0 + 128, k1, LDS + nbufo + HALF_BYTES, tid);
        LGKM(4);                               // aC,bN0 (prev P4 / prologue) returned
        __builtin_amdgcn_s_setprio(1);
#pragma unroll
        for (int mi = 0; mi < 4; ++mi)
#pragma unroll
            for (int nj = 0; nj < 2; ++nj)
#pragma unroll
                for (int ks = 0; ks < 2; ++ks)
                    acc[mi][nj] = __builtin_amdgcn_mfma_f32_16x16x32_bf16(
                        aC[ks][mi], bN0[ks][nj], acc[mi][nj], 0, 0, 0);
        __builtin_amdgcn_s_setprio(0);

        // ---- P2: BAR; read aN(t); stage B0(t+2); MFMA M0N1 (aC x bN1)
        BAR(); SB0();
#pragma unroll
        for (int mi = 0; mi < 4; ++mi) {
            aN[0][mi] = RD(bufo + aO0 + 8192 + mi * 2048);
            aN[1][mi] = RD(bufo + aO1 + 8192 + mi * 2048);
        }
        stage_half(Bt, brow0, k2, LDS + 65536 + bufo, tid);
        LGKM(8);                               // bN1 returned
        __builtin_amdgcn_s_setprio(1);
#pragma unroll
        for (int mi = 0; mi < 4; ++mi)
#pragma unroll
            for (int nj = 0; nj < 2; ++nj)
#pragma unroll
                for (int ks = 0; ks < 2; ++ks)
                    acc[mi][2 + nj] = __builtin_amdgcn_mfma_f32_16x16x32_bf16(
                        aC[ks][mi], bN1[ks][nj], acc[mi][2 + nj], 0, 0, 0);
        __builtin_amdgcn_s_setprio(0);

        // ---- P3: BAR; stage B1(t+2); MFMA M1N0 (aN x bN0)
        BAR(); SB0();
        stage_half(Bt, brow0 + 128, k2, LDS + 65536 + bufo + HALF_BYTES, tid);
        LGKM(0);                               // aN returned
        __builtin_amdgcn_s_setprio(1);
#pragma unroll
        for (int mi = 0; mi < 4; ++mi)
#pragma unroll
            for (int nj = 0; nj < 2; ++nj)
#pragma unroll
                for (int ks = 0; ks < 2; ++ks)
                    acc[4 + mi][nj] = __builtin_amdgcn_mfma_f32_16x16x32_bf16(
                        aN[ks][mi], bN0[ks][nj], acc[4 + mi][nj], 0, 0, 0);
        __builtin_amdgcn_s_setprio(0);

        // ---- P4: vmcnt(4) [t+1 fully staged]; BAR; stage A0(t+2);
        //          read aC,bN0 of t+1 (fly under MFMA); MFMA M1N1 (aN x bN1)
        VMW(4);
        BAR(); SB0();
        stage_half(A, arow0, k2, LDS + bufo, tid);
#pragma unroll
        for (int mi = 0; mi < 4; ++mi) {
            aC[0][mi] = RD(nbufo + aO0 + mi * 2048);
            aC[1][mi] = RD(nbufo + aO1 + mi * 2048);
        }
#pragma unroll
        for (int j = 0; j < 2; ++j) {
            bN0[0][j] = RD(nbufo + bO0 + j * 2048);
            bN0[1][j] = RD(nbufo + bO1 + j * 2048);
        }
        __builtin_amdgcn_s_setprio(1);
#pragma unroll
        for (int mi = 0; mi < 4; ++mi)
#pragma unroll
            for (int nj = 0; nj < 2; ++nj)
#pragma unroll
                for (int ks = 0; ks < 2; ++ks)
                    acc[4 + mi][2 + nj] = __builtin_amdgcn_mfma_f32_16x16x32_bf16(
                        aN[ks][mi], bN1[ks][nj], acc[4 + mi][2 + nj], 0, 0, 0);
        __builtin_amdgcn_s_setprio(0);
    }
#undef RD

    // ---- epilogue: + bias, ReLU, store bf16.  C/D: col=lane&15, row=(lane>>4)*4+reg
    float bb[4];
#pragma unroll
    for (int nj = 0; nj < 4; ++nj)
        bb[nj] = bias[bn * 256 + wn * 64 + nj * 16 + lrow];
#pragma unroll
    for (int mi = 0; mi < 8; ++mi) {
        long row = arow0 + wm * 128 + mi * 16 + (lane >> 4) * 4;
#pragma unroll
        for (int nj = 0; nj < 4; ++nj) {
            int col = bn * 256 + wn * 64 + nj * 16 + lrow;
#pragma unroll
            for (int r = 0; r < 4; ++r) {
                float v = fmaxf(acc[mi][nj][r] + bb[nj], 0.0f);
                H[(row + r) * D_OUT + col] = f2bf(v);
            }
        }
    }
}

// ---------- 4. LayerNorm + mask-pack (dest-indexed; writes EVERY output row) ----------
__global__ void ln_pack_kernel(const short* __restrict__ H,      // bf16 [32768][1024]
                               const int* __restrict__ mask,     // [512][64]
                               const float* __restrict__ ln_w,
                               const float* __restrict__ ln_b,
                               float* __restrict__ out) {        // [512][64][1024]
    int drow = blockIdx.x;           // destination row (b, j)
    int b = drow >> 6, j = drow & 63;
    int tid = threadIdx.x;
    int lane = tid & 63;
    int wave = tid >> 6;
    int base = tid * 4;

    int mv = mask[(b << 6) | lane];
    unsigned long long bal = __ballot(mv != 0);
    int cnt = __popcll(bal);

    float4 o = make_float4(0.f, 0.f, 0.f, 0.f);
    if (j < cnt) {
        int pre = __popcll(bal & ((1ull << lane) - 1ull));
        unsigned long long sel = __ballot(mv != 0 && pre == j);
        int srcn = (int)__builtin_ctzll(sel);
        long row = (long)((b << 6) | srcn);

        short4v hv = *(const short4v*)(H + row * D_OUT + base);
        float v0 = bf2f(hv[0]), v1 = bf2f(hv[1]), v2 = bf2f(hv[2]), v3 = bf2f(hv[3]);

        float s  = v0 + v1 + v2 + v3;
        float s2 = v0 * v0 + v1 * v1 + v2 * v2 + v3 * v3;
#pragma unroll
        for (int off = 32; off > 0; off >>= 1) {
            s  += __shfl_xor(s, off);
            s2 += __shfl_xor(s2, off);
        }
        __shared__ float red[8];
        if (lane == 0) { red[wave] = s; red[wave + 4] = s2; }
        __syncthreads();
        float S  = red[0] + red[1] + red[2] + red[3];
        float S2 = red[4] + red[5] + red[6] + red[7];
        float mu   = S * (1.0f / D_OUT);
        float var  = S2 * (1.0f / D_OUT) - mu * mu;
        float rstd = rsqrtf(var + 1e-12f);

        float4 wv = *(const float4*)(ln_w + base);
        float4 bv = *(const float4*)(ln_b + base);
        o.x = (v0 - mu) * rstd * wv.x + bv.x;
        o.y = (v1 - mu) * rstd * wv.y + bv.y;
        o.z = (v2 - mu) * rstd * wv.z + bv.z;
        o.w = (v3 - mu) * rstd * wv.w + bv.w;
    }
    *(float4*)(out + (long)drow * D_OUT + base) = o;
}

// ---------- launch ----------
extern "C" void kernel_launch(void* const* d_in, const int* in_sizes, int n_in,
                              void* d_out, int out_size, void* d_ws, size_t ws_size,
                              hipStream_t stream) {
    const float* img  = (const float*)d_in[0];
    const int*   mask = (const int*)d_in[2];
    const float* W    = (const float*)d_in[4];
    const float* bias = (const float*)d_in[5];
    const float* lnw  = (const float*)d_in[6];
    const float* lnb  = (const float*)d_in[7];
    float* out = (float*)d_out;

    short* Abf = (short*)d_out;                       // 128 MiB scratch (consumed by GEMM)
    short* Bt  = (short*)d_ws;                        // 4 MiB
    short* H   = (short*)d_ws + (long)D_OUT * D_IN;   // 64 MiB

    cast_a_kernel<<<2048, 256, 0, stream>>>(img, Abf, M_ROWS * D_IN / 8);
    transpose_w_kernel<<<dim3(D_OUT / 32, D_IN / 32), 256, 0, stream>>>(W, Bt);
    gemm256_kernel<<<(M_ROWS / 256) * (D_OUT / 256), 512, 0, stream>>>(Abf, Bt, bias, H);
    ln_pack_kernel<<<M_ROWS, 256, 0, stream>>>(H, mask, lnw, lnb, out);
}